// Round 19
// baseline (328.103 us; speedup 1.0000x reference)
//
#include <hip/hip_runtime.h>
#include <hip/hip_bf16.h>
#include <stdint.h>

typedef __bf16 bf16;
typedef __bf16 bf16x2 __attribute__((ext_vector_type(2)));
typedef __bf16 bf16x4 __attribute__((ext_vector_type(4)));
typedef __bf16 bf16x8 __attribute__((ext_vector_type(8)));
typedef float  f32x4  __attribute__((ext_vector_type(4)));
typedef float  f32x2  __attribute__((ext_vector_type(2)));

#define NROWS 262144
#define GSEG  65536
#define DIN   512
#define DMID  256
#define DGAT  128
#define DOUT  256

// ---- workspace layout (bytes) ----
#define OFF_W2S   0u           // [256][512] bf16, K pre-swizzled
#define OFF_W3T   262144u      // [128][256] bf16, plain [col][k]
#define OFF_GWT   327680u      // [128][128] bf16, plain [col][k]
#define OFF_PWT   360448u      // [256][128] bf16, plain [col][k]
#define OFF_BNS   425984u      // [256] f32
#define OFF_BNB   427008u      // [256] f32
#define OFF_RS    428032u      // [65537] int
#define OFF_H2    1048576u     // [NROWS][128] bf16 = 64 MB
#define OFF_G     68157440u    // [NROWS][128] bf16 = 64 MB
#define OFF_E     135266304u   // [NROWS] f32 = 1 MB

// ---------------- prep (weights) + rowstart (segment boundaries), merged ----------------
__global__ __launch_bounds__(256) void k_prep(
    const float* __restrict__ w2, const float* __restrict__ w3, const float* __restrict__ gw,
    const float* __restrict__ pw,
    const float* __restrict__ b2, const float* __restrict__ bn_g, const float* __restrict__ bn_b,
    const float* __restrict__ bn_m, const float* __restrict__ bn_v,
    const int* __restrict__ seg,
    bf16* __restrict__ w2s, bf16* __restrict__ w3t, bf16* __restrict__ gwt,
    bf16* __restrict__ pwt, float* __restrict__ bnS, float* __restrict__ bnB,
    int* __restrict__ rs) {
  int idx = blockIdx.x * 256 + threadIdx.x;
  if (idx < DIN * DMID) {
    int k = idx / DMID, c = idx % DMID;
    int kk = k & 63, kb = k & ~63;
    w2s[c * DIN + kb + (kk ^ ((c & 7) << 3))] = (bf16)w2[idx];
  }
  if (idx < DMID * DGAT) {
    int k = idx / DGAT, c = idx % DGAT;
    w3t[c * DMID + k] = (bf16)w3[idx];
  }
  if (idx < DGAT * DGAT) {
    int k = idx / DGAT, c = idx % DGAT;
    gwt[c * DGAT + k] = (bf16)gw[idx];
  }
  if (idx < DOUT * DGAT) {
    int c = idx >> 7, k = idx & 127;          // pwt[c][k] = pw[k][c]
    pwt[idx] = (bf16)pw[k * DOUT + c];
  }
  if (idx < DMID) {
    float s = bn_g[idx] * rsqrtf(bn_v[idx] + 1e-5f);
    bnS[idx] = s;
    bnB[idx] = s * (b2[idx] - bn_m[idx]) + bn_b[idx];
  }
  if (idx < NROWS) {
    int s = seg[idx];
    if (idx == 0) rs[s] = 0;
    else if (seg[idx - 1] != s) rs[s] = idx;
    if (idx == NROWS - 1) rs[GSEG] = NROWS;
  }
}

// ---------------- mega encoder (R16 proven form + T5 setprio around MFMA clusters) ----------------
__global__ __launch_bounds__(256, 2) void k_enc(
    const float* __restrict__ x, const bf16* __restrict__ w2s,
    const bf16* __restrict__ w3t, const bf16* __restrict__ gwt,
    const float* __restrict__ bnS, const float* __restrict__ bnB,
    const float* __restrict__ b3, const float* __restrict__ gb, const float* __restrict__ ga,
    bf16* __restrict__ h2, bf16* __restrict__ g, float* __restrict__ e) {
  __shared__ bf16 u[32768];      // 64 KB
  __shared__ float eP[256];
  bf16* As  = u;                 // [128][64] swz        (phase A)
  bf16* Bs  = u + 8192;          // [256][64] swz-content (phase A)
  bf16* H1s = u;                 // [128][256] swz/64blk  (phase A out / B in)
  bf16* Hs  = u;                 // [128][128] swz        (phase B out / C in)
  bf16* Gs  = u + 16384;         // [128][128] swz        (phase C out)
  const int t = threadIdx.x;
  const int mBase = blockIdx.x * 128;
  const int ph0 = ((blockIdx.x >> 8) & 1) * 4;   // anti-phase for co-resident pairs
  const int w = t >> 6, l = t & 63;
  const int wm = w >> 1, wn = w & 1;
  const int l15 = l & 15, lh = l >> 4;
  const f32x4 zero = {0.f, 0.f, 0.f, 0.f};

  // ---------------- phase A ----------------
  const int ar = t >> 1;
  const int ak = (t & 1) * 32;
  const float* xp = x + (size_t)(mBase + ar) * DIN + ak;
  const int aswz = (ar & 7) << 3;
  const int bcol0 = w * 64 + (l >> 3);
  const int bkk = (l & 7) * 8;
  bf16* bsw = Bs + (w * 8) * 512 + l * 8;   // thread's Bs write base (instr i -> +i*512)

  f32x4 acc[4][8];
#pragma unroll
  for (int m = 0; m < 4; m++)
#pragma unroll
    for (int n = 0; n < 8; n++) acc[m][n] = zero;

  float4 pf[8];
  bf16x8 brg[8];
  {
    const int kks = ph0;   // first tile
#pragma unroll
    for (int j = 0; j < 8; j++) pf[j] = *(const float4*)(xp + kks * 64 + j * 4);
#pragma unroll
    for (int i = 0; i < 8; i++)
      brg[i] = *(const bf16x8*)(w2s + (size_t)(bcol0 + i * 8) * DIN + kks * 64 + bkk);
  }

  for (int kt = 0; kt < 8; ++kt) {
    const int kk0 = (kt + ph0) & 7;          // rotated K-tile index
    __syncthreads();   // B1: prev MFMA done with As/Bs; drains loads issued a full phase ago
    // convert x (after B1: extends load window by barrier-wait)
    bf16x8 av[4];
#pragma unroll
    for (int j = 0; j < 4; j++) {
      av[j][0] = (bf16)pf[2 * j].x; av[j][1] = (bf16)pf[2 * j].y;
      av[j][2] = (bf16)pf[2 * j].z; av[j][3] = (bf16)pf[2 * j].w;
      av[j][4] = (bf16)pf[2 * j + 1].x; av[j][5] = (bf16)pf[2 * j + 1].y;
      av[j][6] = (bf16)pf[2 * j + 1].z; av[j][7] = (bf16)pf[2 * j + 1].w;
    }
#pragma unroll
    for (int j = 0; j < 4; j++)
      *(bf16x8*)(As + ar * 64 + ((ak + 8 * j) ^ aswz)) = av[j];
#pragma unroll
    for (int i = 0; i < 8; i++)
      *(bf16x8*)(bsw + i * 512) = brg[i];
    __syncthreads();   // B2: only ds_writes outstanding (no vmem) -> cheap
    // issue next tile's loads; they fly through the whole MFMA phase
    if (kt < 7) {
      const int kk1 = (kk0 + 1) & 7;
#pragma unroll
      for (int j = 0; j < 8; j++) pf[j] = *(const float4*)(xp + kk1 * 64 + j * 4);
#pragma unroll
      for (int i = 0; i < 8; i++)
        brg[i] = *(const bf16x8*)(w2s + (size_t)(bcol0 + i * 8) * DIN + kk1 * 64 + bkk);
    }
    __builtin_amdgcn_s_setprio(1);   // T5: favor MFMA-phase wave vs load-phase partner block
#pragma unroll
    for (int ks = 0; ks < 2; ++ks) {
      const int kofs = ks * 32 + lh * 8;
      bf16x8 a[4], b[8];
#pragma unroll
      for (int m = 0; m < 4; m++) {
        int r = wm * 64 + m * 16 + l15;
        a[m] = *(const bf16x8*)(As + r * 64 + (kofs ^ ((r & 7) << 3)));
      }
#pragma unroll
      for (int n = 0; n < 8; n++) {
        int c = wn * 128 + n * 16 + l15;
        b[n] = *(const bf16x8*)(Bs + c * 64 + (kofs ^ ((c & 7) << 3)));
      }
#pragma unroll
      for (int m = 0; m < 4; m++)
#pragma unroll
        for (int n = 0; n < 8; n++)
          acc[m][n] = __builtin_amdgcn_mfma_f32_16x16x32_bf16(b[n], a[m], acc[m][n], 0, 0, 0);
    }
    __builtin_amdgcn_s_setprio(0);
  }
  __syncthreads();

  const int rsw = (l15 & 7) << 3;
#pragma unroll
  for (int n = 0; n < 8; n++) {
    int c0 = wn * 128 + n * 16 + lh * 4;
    f32x4 s4 = *(const f32x4*)(bnS + c0);
    f32x4 b4 = *(const f32x4*)(bnB + c0);
    int cs = (c0 & ~63) + ((c0 & 63) ^ rsw);
#pragma unroll
    for (int m = 0; m < 4; m++) {
      int rl = wm * 64 + m * 16 + l15;
      bf16x4 o;
#pragma unroll
      for (int q = 0; q < 4; q++) {
        float v = acc[m][n][q] * s4[q] + b4[q];
        o[q] = (bf16)(v > 0.f ? v : 0.f);
      }
      *(bf16x4*)(H1s + rl * 256 + cs) = o;
    }
  }
  __syncthreads();

  // ---------------- phase B: h2 = relu(h1@w3+b3) ----------------
  f32x4 acc2[4][4];
#pragma unroll
  for (int m = 0; m < 4; m++)
#pragma unroll
    for (int n = 0; n < 4; n++) acc2[m][n] = zero;
  __builtin_amdgcn_s_setprio(1);
#pragma unroll
  for (int ks = 0; ks < 8; ++ks) {
    const int kofs = ks * 32 + lh * 8;
    const int kb = kofs & ~63, kk = kofs & 63;
    bf16x8 a[4], b[4];
#pragma unroll
    for (int n = 0; n < 4; n++) {
      int c = wn * 64 + n * 16 + l15;
      b[n] = *(const bf16x8*)(w3t + (size_t)c * DMID + kofs);
    }
#pragma unroll
    for (int m = 0; m < 4; m++) {
      int r = wm * 64 + m * 16 + l15;
      a[m] = *(const bf16x8*)(H1s + r * 256 + kb + (kk ^ ((r & 7) << 3)));
    }
#pragma unroll
    for (int m = 0; m < 4; m++)
#pragma unroll
      for (int n = 0; n < 4; n++)
        acc2[m][n] = __builtin_amdgcn_mfma_f32_16x16x32_bf16(b[n], a[m], acc2[m][n], 0, 0, 0);
  }
  __builtin_amdgcn_s_setprio(0);
  __syncthreads();   // done reading H1s; Hs may overwrite

  // epilogue B: relu+bias -> bf16 into Hs (LDS only; global write deferred)
#pragma unroll
  for (int n = 0; n < 4; n++) {
    int c0 = wn * 64 + n * 16 + lh * 4;
    f32x4 b4 = *(const f32x4*)(b3 + c0);
#pragma unroll
    for (int m = 0; m < 4; m++) {
      int rl = wm * 64 + m * 16 + l15;
      bf16x4 hb;
#pragma unroll
      for (int q = 0; q < 4; q++) {
        float v = acc2[m][n][q] + b4[q];
        hb[q] = (bf16)(v > 0.f ? v : 0.f);
      }
      *(bf16x4*)(Hs + rl * 128 + (c0 ^ ((rl & 7) << 3))) = hb;
    }
  }
  __syncthreads();

  // ---------------- phase C: g = h2@gw+gb; e = g.ga ----------------
  f32x4 gacc[4][4];
#pragma unroll
  for (int m = 0; m < 4; m++)
#pragma unroll
    for (int n = 0; n < 4; n++) gacc[m][n] = zero;
  __builtin_amdgcn_s_setprio(1);
#pragma unroll
  for (int ks = 0; ks < 4; ++ks) {
    const int kofs = ks * 32 + lh * 8;
    bf16x8 a[4], b[4];
#pragma unroll
    for (int n = 0; n < 4; n++) {
      int c = wn * 64 + n * 16 + l15;
      b[n] = *(const bf16x8*)(gwt + (size_t)c * DGAT + kofs);
    }
#pragma unroll
    for (int m = 0; m < 4; m++) {
      int r = wm * 64 + m * 16 + l15;
      a[m] = *(const bf16x8*)(Hs + r * 128 + (kofs ^ ((r & 7) << 3)));
    }
#pragma unroll
    for (int m = 0; m < 4; m++)
#pragma unroll
      for (int n = 0; n < 4; n++)
        gacc[m][n] = __builtin_amdgcn_mfma_f32_16x16x32_bf16(b[n], a[m], gacc[m][n], 0, 0, 0);
  }
  __builtin_amdgcn_s_setprio(0);
  // epilogue C: gv -> Gs (LDS); e partials
  float ep[4] = {0.f, 0.f, 0.f, 0.f};
#pragma unroll
  for (int n = 0; n < 4; n++) {
    int c0 = wn * 64 + n * 16 + lh * 4;
    f32x4 gb4 = *(const f32x4*)(gb + c0);
    f32x4 ga4 = *(const f32x4*)(ga + c0);
#pragma unroll
    for (int m = 0; m < 4; m++) {
      int rl = wm * 64 + m * 16 + l15;
      bf16x4 gv;
#pragma unroll
      for (int q = 0; q < 4; q++) gv[q] = (bf16)(gacc[m][n][q] + gb4[q]);
      *(bf16x4*)(Gs + rl * 128 + (c0 ^ ((rl & 7) << 3))) = gv;
#pragma unroll
      for (int q = 0; q < 4; q++) ep[m] += (float)gv[q] * ga4[q];
    }
  }
#pragma unroll
  for (int m = 0; m < 4; m++) {
    float v = ep[m];
    v += __shfl_xor(v, 16, 64);
    v += __shfl_xor(v, 32, 64);
    if (l < 16) eP[(wm * 64 + m * 16 + l) * 2 + wn] = v;
  }
  __syncthreads();   // Gs/Hs final + eP ready

  // ---------------- coalesced dump: Hs->h2, Gs->g ----------------
  const int drow = t >> 4;            // 0..15
  const int dc = (t & 15) * 8;        // elem offset in row
#pragma unroll
  for (int i = 0; i < 8; ++i) {
    int rl = i * 16 + drow;
    int cs = dc ^ ((rl & 7) << 3);
    *(bf16x8*)(h2 + (size_t)(mBase + rl) * DGAT + dc) = *(const bf16x8*)(Hs + rl * 128 + cs);
    *(bf16x8*)(g  + (size_t)(mBase + rl) * DGAT + dc) = *(const bf16x8*)(Gs + rl * 128 + cs);
  }
  if (t < 128) e[mBase + t] = eP[t * 2] + eP[t * 2 + 1];
}

// ---------------- fused segment pool (4x16 split, pass1+2 merged online) + proj + L2 norm ----------------
__global__ __launch_bounds__(256) void k_segproj(
    const float* __restrict__ e, const bf16* __restrict__ g, const bf16* __restrict__ h2,
    const int* __restrict__ rs, const bf16* __restrict__ pwt, const float* __restrict__ pb,
    float* __restrict__ out) {
  __shared__ bf16 objs[16 * 128];   // K-swizzled
  __shared__ float red[16 * 4];
  const int t = threadIdx.x;
  const int w = t >> 6, l = t & 63;
  const int l15 = l & 15, lh = l >> 4;
  const int gBase = blockIdx.x * 16;
  const f32x4 zero = {0.f, 0.f, 0.f, 0.f};

  // ---- segment phase: group grp owns segment sl = w*4+grp; lane ld owns dims ld*8..+7
  {
    const int grp = l >> 4;
    const int ld = l & 15;
    const int sl = w * 4 + grp;
    const int s = gBase + sl;
    const int r0 = rs[s], r1 = rs[s + 1];
    const int len = r1 - r0;
    int maxlen = len;
    maxlen = max(maxlen, __shfl_xor(maxlen, 16, 64));
    maxlen = max(maxlen, __shfl_xor(maxlen, 32, 64));

    // pass 1 (merged): online softmax max+denom+weighted g-sum
    float m = -3.4e38f, den = 0.f;
    float p[8];
#pragma unroll
    for (int q = 0; q < 8; q++) p[q] = 0.f;
    for (int i = 0; i < maxlen; ++i) {
      int r = min(r0 + i, r1 - 1);
      float ev = e[r];
      bf16x8 gv = *(const bf16x8*)(g + (size_t)r * DGAT + ld * 8);
      float evv = (i < len) ? ev : -3.4e38f;
      float mn = fmaxf(m, evv);
      float cor = __expf(m - mn);      // 0 on first iter; 1 when max unchanged
      float wr = __expf(evv - mn);     // 0 for padded rows
      den = den * cor + wr;
#pragma unroll
      for (int q = 0; q < 8; q++) p[q] = p[q] * cor + wr * (float)gv[q];
      m = mn;
    }
    float inv = 1.f / den;
#pragma unroll
    for (int q = 0; q < 8; q++) p[q] *= inv;
    // pass 2: residual + relu + segment max (mask to 0, no-op under max since om>=0)
    float om[8];
#pragma unroll
    for (int q = 0; q < 8; q++) om[q] = 0.f;
    for (int i = 0; i < maxlen; ++i) {
      int r = min(r0 + i, r1 - 1);
      bf16x8 hv = *(const bf16x8*)(h2 + (size_t)r * DGAT + ld * 8);
#pragma unroll
      for (int q = 0; q < 8; q++) {
        float a = fmaxf((float)hv[q] + p[q], 0.f);
        om[q] = fmaxf(om[q], (i < len) ? a : 0.f);
      }
    }
    bf16x8 ob;
#pragma unroll
    for (int q = 0; q < 8; q++) ob[q] = (bf16)om[q];
    int kofs = (ld * 8) ^ ((sl & 7) << 3);   // 8-aligned offset, XOR bits 3-5 -> stays 8-aligned
    *(bf16x8*)(objs + sl * 128 + kofs) = ob;
  }
  __syncthreads();

  // ---- proj phase: out[16 x 256] = obj @ pw + pb via MFMA
  f32x4 acc[4];
#pragma unroll
  for (int n = 0; n < 4; n++) acc[n] = zero;
#pragma unroll
  for (int ks = 0; ks < 4; ++ks) {
    const int kofs = ks * 32 + lh * 8;
    bf16x8 a = *(const bf16x8*)(objs + l15 * 128 + (kofs ^ ((l15 & 7) << 3)));
#pragma unroll
    for (int n = 0; n < 4; n++) {
      int c = w * 64 + n * 16 + l15;
      bf16x8 b = *(const bf16x8*)(pwt + (size_t)c * DGAT + kofs);
      acc[n] = __builtin_amdgcn_mfma_f32_16x16x32_bf16(b, a, acc[n], 0, 0, 0);
    }
  }
  float s2 = 0.f;
#pragma unroll
  for (int n = 0; n < 4; n++) {
    int c0 = w * 64 + n * 16 + lh * 4;
    f32x4 p4 = *(const f32x4*)(pb + c0);
#pragma unroll
    for (int q = 0; q < 4; q++) {
      acc[n][q] += p4[q];
      s2 += acc[n][q] * acc[n][q];
    }
  }
  s2 += __shfl_xor(s2, 16, 64);
  s2 += __shfl_xor(s2, 32, 64);
  if (l < 16) red[l * 4 + w] = s2;
  __syncthreads();
  float tot = red[l15 * 4 + 0] + red[l15 * 4 + 1] + red[l15 * 4 + 2] + red[l15 * 4 + 3];
  float rinv = 1.f / (sqrtf(tot) + 1e-9f);
#pragma unroll
  for (int n = 0; n < 4; n++) {
    int c0 = w * 64 + n * 16 + lh * 4;
    f32x4 o;
#pragma unroll
    for (int q = 0; q < 4; q++) o[q] = acc[n][q] * rinv;
    *(f32x4*)(out + (size_t)(gBase + l15) * DOUT + c0) = o;
  }
}

extern "C" void kernel_launch(void* const* d_in, const int* in_sizes, int n_in,
                              void* d_out, int out_size, void* d_ws, size_t ws_size,
                              hipStream_t stream) {
  const float* x    = (const float*)d_in[0];
  const int*   seg  = (const int*)d_in[1];
  const float* w2   = (const float*)d_in[2];
  const float* b2   = (const float*)d_in[3];
  const float* bn_g = (const float*)d_in[4];
  const float* bn_b = (const float*)d_in[5];
  const float* bn_m = (const float*)d_in[6];
  const float* bn_v = (const float*)d_in[7];
  const float* w3   = (const float*)d_in[8];
  const float* b3   = (const float*)d_in[9];
  const float* gw   = (const float*)d_in[10];
  const float* gb   = (const float*)d_in[11];
  const float* ga   = (const float*)d_in[12];
  const float* pw   = (const float*)d_in[13];
  const float* pb   = (const float*)d_in[14];

  char* ws = (char*)d_ws;
  bf16*  w2s = (bf16*)(ws + OFF_W2S);
  bf16*  w3t = (bf16*)(ws + OFF_W3T);
  bf16*  gwt = (bf16*)(ws + OFF_GWT);
  bf16*  pwt = (bf16*)(ws + OFF_PWT);
  float* bnS = (float*)(ws + OFF_BNS);
  float* bnB = (float*)(ws + OFF_BNB);
  int*   rs  = (int*)(ws + OFF_RS);
  bf16*  h2  = (bf16*)(ws + OFF_H2);
  bf16*  g   = (bf16*)(ws + OFF_G);
  float* e   = (float*)(ws + OFF_E);
  float* out = (float*)d_out;

  k_prep<<<NROWS / 256, 256, 0, stream>>>(w2, w3, gw, pw, b2, bn_g, bn_b, bn_m, bn_v,
                                          seg, w2s, w3t, gwt, pwt, bnS, bnB, rs);
  k_enc<<<NROWS / 128, 256, 0, stream>>>(x, w2s, w3t, gwt, bnS, bnB, b3, gb, ga, h2, g, e);
  k_segproj<<<GSEG / 16, 256, 0, stream>>>(e, g, h2, rs, pwt, pb, out);
}

// Round 20
// 281.258 us; speedup vs baseline: 1.1666x; 1.1666x over previous
//
#include <hip/hip_runtime.h>
#include <hip/hip_bf16.h>
#include <stdint.h>

typedef __bf16 bf16;
typedef __bf16 bf16x2 __attribute__((ext_vector_type(2)));
typedef __bf16 bf16x4 __attribute__((ext_vector_type(4)));
typedef __bf16 bf16x8 __attribute__((ext_vector_type(8)));
typedef float  f32x4  __attribute__((ext_vector_type(4)));
typedef float  f32x2  __attribute__((ext_vector_type(2)));

#define NROWS 262144
#define GSEG  65536
#define DIN   512
#define DMID  256
#define DGAT  128
#define DOUT  256

// ---- workspace layout (bytes) ----
#define OFF_W2S   0u           // [256][512] bf16, K pre-swizzled
#define OFF_W3T   262144u      // [128][256] bf16, plain [col][k]
#define OFF_GWT   327680u      // [128][128] bf16, plain [col][k]
#define OFF_PWT   360448u      // [256][128] bf16, plain [col][k]
#define OFF_BNS   425984u      // [256] f32
#define OFF_BNB   427008u      // [256] f32
#define OFF_RS    428032u      // [65537] int
#define OFF_H2    1048576u     // [NROWS][128] bf16 = 64 MB
#define OFF_G     68157440u    // [NROWS][128] bf16 = 64 MB
#define OFF_E     135266304u   // [NROWS] f32 = 1 MB

// ---------------- prep (weights) + rowstart (segment boundaries), merged ----------------
__global__ __launch_bounds__(256) void k_prep(
    const float* __restrict__ w2, const float* __restrict__ w3, const float* __restrict__ gw,
    const float* __restrict__ pw,
    const float* __restrict__ b2, const float* __restrict__ bn_g, const float* __restrict__ bn_b,
    const float* __restrict__ bn_m, const float* __restrict__ bn_v,
    const int* __restrict__ seg,
    bf16* __restrict__ w2s, bf16* __restrict__ w3t, bf16* __restrict__ gwt,
    bf16* __restrict__ pwt, float* __restrict__ bnS, float* __restrict__ bnB,
    int* __restrict__ rs) {
  int idx = blockIdx.x * 256 + threadIdx.x;
  if (idx < DIN * DMID) {
    int k = idx / DMID, c = idx % DMID;
    int kk = k & 63, kb = k & ~63;
    w2s[c * DIN + kb + (kk ^ ((c & 7) << 3))] = (bf16)w2[idx];
  }
  if (idx < DMID * DGAT) {
    int k = idx / DGAT, c = idx % DGAT;
    w3t[c * DMID + k] = (bf16)w3[idx];
  }
  if (idx < DGAT * DGAT) {
    int k = idx / DGAT, c = idx % DGAT;
    gwt[c * DGAT + k] = (bf16)gw[idx];
  }
  if (idx < DOUT * DGAT) {
    int c = idx >> 7, k = idx & 127;          // pwt[c][k] = pw[k][c]
    pwt[idx] = (bf16)pw[k * DOUT + c];
  }
  if (idx < DMID) {
    float s = bn_g[idx] * rsqrtf(bn_v[idx] + 1e-5f);
    bnS[idx] = s;
    bnB[idx] = s * (b2[idx] - bn_m[idx]) + bn_b[idx];
  }
  if (idx < NROWS) {
    int s = seg[idx];
    if (idx == 0) rs[s] = 0;
    else if (seg[idx - 1] != s) rs[s] = idx;
    if (idx == NROWS - 1) rs[GSEG] = NROWS;
  }
}

// ---------------- mega encoder (R16 proven form: reg-staged B, zero-vmem-at-B2) ----------------
// Per kt: B1 drains loads issued one full phase earlier; convert+ds_writes between
// barriers (no global issue there); next-tile x & B loads issued after B2 fly
// through the whole MFMA phase. Anti-phase kt stagger across co-resident blocks.
__global__ __launch_bounds__(256, 2) void k_enc(
    const float* __restrict__ x, const bf16* __restrict__ w2s,
    const bf16* __restrict__ w3t, const bf16* __restrict__ gwt,
    const float* __restrict__ bnS, const float* __restrict__ bnB,
    const float* __restrict__ b3, const float* __restrict__ gb, const float* __restrict__ ga,
    bf16* __restrict__ h2, bf16* __restrict__ g, float* __restrict__ e) {
  __shared__ bf16 u[32768];      // 64 KB
  __shared__ float eP[256];
  bf16* As  = u;                 // [128][64] swz        (phase A)
  bf16* Bs  = u + 8192;          // [256][64] swz-content (phase A)
  bf16* H1s = u;                 // [128][256] swz/64blk  (phase A out / B in)
  bf16* Hs  = u;                 // [128][128] swz        (phase B out / C in)
  bf16* Gs  = u + 16384;         // [128][128] swz        (phase C out)
  const int t = threadIdx.x;
  const int mBase = blockIdx.x * 128;
  const int ph0 = ((blockIdx.x >> 8) & 1) * 4;   // anti-phase for co-resident pairs
  const int w = t >> 6, l = t & 63;
  const int wm = w >> 1, wn = w & 1;
  const int l15 = l & 15, lh = l >> 4;
  const f32x4 zero = {0.f, 0.f, 0.f, 0.f};

  // ---------------- phase A ----------------
  const int ar = t >> 1;
  const int ak = (t & 1) * 32;
  const float* xp = x + (size_t)(mBase + ar) * DIN + ak;
  const int aswz = (ar & 7) << 3;
  const int bcol0 = w * 64 + (l >> 3);
  const int bkk = (l & 7) * 8;
  bf16* bsw = Bs + (w * 8) * 512 + l * 8;   // thread's Bs write base (instr i -> +i*512)

  f32x4 acc[4][8];
#pragma unroll
  for (int m = 0; m < 4; m++)
#pragma unroll
    for (int n = 0; n < 8; n++) acc[m][n] = zero;

  float4 pf[8];
  bf16x8 brg[8];
  {
    const int kks = ph0;   // first tile
#pragma unroll
    for (int j = 0; j < 8; j++) pf[j] = *(const float4*)(xp + kks * 64 + j * 4);
#pragma unroll
    for (int i = 0; i < 8; i++)
      brg[i] = *(const bf16x8*)(w2s + (size_t)(bcol0 + i * 8) * DIN + kks * 64 + bkk);
  }

  for (int kt = 0; kt < 8; ++kt) {
    const int kk0 = (kt + ph0) & 7;          // rotated K-tile index
    __syncthreads();   // B1: prev MFMA done with As/Bs; drains loads issued a full phase ago
    // convert x (after B1: extends load window by barrier-wait)
    bf16x8 av[4];
#pragma unroll
    for (int j = 0; j < 4; j++) {
      av[j][0] = (bf16)pf[2 * j].x; av[j][1] = (bf16)pf[2 * j].y;
      av[j][2] = (bf16)pf[2 * j].z; av[j][3] = (bf16)pf[2 * j].w;
      av[j][4] = (bf16)pf[2 * j + 1].x; av[j][5] = (bf16)pf[2 * j + 1].y;
      av[j][6] = (bf16)pf[2 * j + 1].z; av[j][7] = (bf16)pf[2 * j + 1].w;
    }
#pragma unroll
    for (int j = 0; j < 4; j++)
      *(bf16x8*)(As + ar * 64 + ((ak + 8 * j) ^ aswz)) = av[j];
#pragma unroll
    for (int i = 0; i < 8; i++)
      *(bf16x8*)(bsw + i * 512) = brg[i];
    __syncthreads();   // B2: only ds_writes outstanding (no vmem) -> cheap
    // issue next tile's loads; they fly through the whole MFMA phase
    if (kt < 7) {
      const int kk1 = (kk0 + 1) & 7;
#pragma unroll
      for (int j = 0; j < 8; j++) pf[j] = *(const float4*)(xp + kk1 * 64 + j * 4);
#pragma unroll
      for (int i = 0; i < 8; i++)
        brg[i] = *(const bf16x8*)(w2s + (size_t)(bcol0 + i * 8) * DIN + kk1 * 64 + bkk);
    }
#pragma unroll
    for (int ks = 0; ks < 2; ++ks) {
      const int kofs = ks * 32 + lh * 8;
      bf16x8 a[4], b[8];
#pragma unroll
      for (int m = 0; m < 4; m++) {
        int r = wm * 64 + m * 16 + l15;
        a[m] = *(const bf16x8*)(As + r * 64 + (kofs ^ ((r & 7) << 3)));
      }
#pragma unroll
      for (int n = 0; n < 8; n++) {
        int c = wn * 128 + n * 16 + l15;
        b[n] = *(const bf16x8*)(Bs + c * 64 + (kofs ^ ((c & 7) << 3)));
      }
#pragma unroll
      for (int m = 0; m < 4; m++)
#pragma unroll
        for (int n = 0; n < 8; n++)
          acc[m][n] = __builtin_amdgcn_mfma_f32_16x16x32_bf16(b[n], a[m], acc[m][n], 0, 0, 0);
    }
  }
  __syncthreads();

  const int rsw = (l15 & 7) << 3;
#pragma unroll
  for (int n = 0; n < 8; n++) {
    int c0 = wn * 128 + n * 16 + lh * 4;
    f32x4 s4 = *(const f32x4*)(bnS + c0);
    f32x4 b4 = *(const f32x4*)(bnB + c0);
    int cs = (c0 & ~63) + ((c0 & 63) ^ rsw);
#pragma unroll
    for (int m = 0; m < 4; m++) {
      int rl = wm * 64 + m * 16 + l15;
      bf16x4 o;
#pragma unroll
      for (int q = 0; q < 4; q++) {
        float v = acc[m][n][q] * s4[q] + b4[q];
        o[q] = (bf16)(v > 0.f ? v : 0.f);
      }
      *(bf16x4*)(H1s + rl * 256 + cs) = o;
    }
  }
  __syncthreads();

  // ---------------- phase B: h2 = relu(h1@w3+b3) ----------------
  f32x4 acc2[4][4];
#pragma unroll
  for (int m = 0; m < 4; m++)
#pragma unroll
    for (int n = 0; n < 4; n++) acc2[m][n] = zero;
#pragma unroll
  for (int ks = 0; ks < 8; ++ks) {
    const int kofs = ks * 32 + lh * 8;
    const int kb = kofs & ~63, kk = kofs & 63;
    bf16x8 a[4], b[4];
#pragma unroll
    for (int n = 0; n < 4; n++) {
      int c = wn * 64 + n * 16 + l15;
      b[n] = *(const bf16x8*)(w3t + (size_t)c * DMID + kofs);
    }
#pragma unroll
    for (int m = 0; m < 4; m++) {
      int r = wm * 64 + m * 16 + l15;
      a[m] = *(const bf16x8*)(H1s + r * 256 + kb + (kk ^ ((r & 7) << 3)));
    }
#pragma unroll
    for (int m = 0; m < 4; m++)
#pragma unroll
      for (int n = 0; n < 4; n++)
        acc2[m][n] = __builtin_amdgcn_mfma_f32_16x16x32_bf16(b[n], a[m], acc2[m][n], 0, 0, 0);
  }
  __syncthreads();   // done reading H1s; Hs may overwrite

  // epilogue B: relu+bias -> bf16 into Hs (LDS only; global write deferred)
#pragma unroll
  for (int n = 0; n < 4; n++) {
    int c0 = wn * 64 + n * 16 + lh * 4;
    f32x4 b4 = *(const f32x4*)(b3 + c0);
#pragma unroll
    for (int m = 0; m < 4; m++) {
      int rl = wm * 64 + m * 16 + l15;
      bf16x4 hb;
#pragma unroll
      for (int q = 0; q < 4; q++) {
        float v = acc2[m][n][q] + b4[q];
        hb[q] = (bf16)(v > 0.f ? v : 0.f);
      }
      *(bf16x4*)(Hs + rl * 128 + (c0 ^ ((rl & 7) << 3))) = hb;
    }
  }
  __syncthreads();

  // ---------------- phase C: g = h2@gw+gb; e = g.ga ----------------
  f32x4 gacc[4][4];
#pragma unroll
  for (int m = 0; m < 4; m++)
#pragma unroll
    for (int n = 0; n < 4; n++) gacc[m][n] = zero;
#pragma unroll
  for (int ks = 0; ks < 4; ++ks) {
    const int kofs = ks * 32 + lh * 8;
    bf16x8 a[4], b[4];
#pragma unroll
    for (int n = 0; n < 4; n++) {
      int c = wn * 64 + n * 16 + l15;
      b[n] = *(const bf16x8*)(gwt + (size_t)c * DGAT + kofs);
    }
#pragma unroll
    for (int m = 0; m < 4; m++) {
      int r = wm * 64 + m * 16 + l15;
      a[m] = *(const bf16x8*)(Hs + r * 128 + (kofs ^ ((r & 7) << 3)));
    }
#pragma unroll
    for (int m = 0; m < 4; m++)
#pragma unroll
      for (int n = 0; n < 4; n++)
        gacc[m][n] = __builtin_amdgcn_mfma_f32_16x16x32_bf16(b[n], a[m], gacc[m][n], 0, 0, 0);
  }
  // epilogue C: gv -> Gs (LDS); e partials
  float ep[4] = {0.f, 0.f, 0.f, 0.f};
#pragma unroll
  for (int n = 0; n < 4; n++) {
    int c0 = wn * 64 + n * 16 + lh * 4;
    f32x4 gb4 = *(const f32x4*)(gb + c0);
    f32x4 ga4 = *(const f32x4*)(ga + c0);
#pragma unroll
    for (int m = 0; m < 4; m++) {
      int rl = wm * 64 + m * 16 + l15;
      bf16x4 gv;
#pragma unroll
      for (int q = 0; q < 4; q++) gv[q] = (bf16)(gacc[m][n][q] + gb4[q]);
      *(bf16x4*)(Gs + rl * 128 + (c0 ^ ((rl & 7) << 3))) = gv;
#pragma unroll
      for (int q = 0; q < 4; q++) ep[m] += (float)gv[q] * ga4[q];
    }
  }
#pragma unroll
  for (int m = 0; m < 4; m++) {
    float v = ep[m];
    v += __shfl_xor(v, 16, 64);
    v += __shfl_xor(v, 32, 64);
    if (l < 16) eP[(wm * 64 + m * 16 + l) * 2 + wn] = v;
  }
  __syncthreads();   // Gs/Hs final + eP ready

  // ---------------- coalesced dump: Hs->h2, Gs->g ----------------
  const int drow = t >> 4;            // 0..15
  const int dc = (t & 15) * 8;        // elem offset in row
#pragma unroll
  for (int i = 0; i < 8; ++i) {
    int rl = i * 16 + drow;
    int cs = dc ^ ((rl & 7) << 3);
    *(bf16x8*)(h2 + (size_t)(mBase + rl) * DGAT + dc) = *(const bf16x8*)(Hs + rl * 128 + cs);
    *(bf16x8*)(g  + (size_t)(mBase + rl) * DGAT + dc) = *(const bf16x8*)(Gs + rl * 128 + cs);
  }
  if (t < 128) e[mBase + t] = eP[t * 2] + eP[t * 2 + 1];
}

// ---------------- fused segment pool (4x16 split, pass1+2 merged online) + proj + L2 norm ----------------
__global__ __launch_bounds__(256) void k_segproj(
    const float* __restrict__ e, const bf16* __restrict__ g, const bf16* __restrict__ h2,
    const int* __restrict__ rs, const bf16* __restrict__ pwt, const float* __restrict__ pb,
    float* __restrict__ out) {
  __shared__ bf16 objs[16 * 128];   // K-swizzled
  __shared__ float red[16 * 4];
  const int t = threadIdx.x;
  const int w = t >> 6, l = t & 63;
  const int l15 = l & 15, lh = l >> 4;
  const int gBase = blockIdx.x * 16;
  const f32x4 zero = {0.f, 0.f, 0.f, 0.f};

  // ---- segment phase: group grp owns segment sl = w*4+grp; lane ld owns dims ld*8..+7
  {
    const int grp = l >> 4;
    const int ld = l & 15;
    const int sl = w * 4 + grp;
    const int s = gBase + sl;
    const int r0 = rs[s], r1 = rs[s + 1];
    const int len = r1 - r0;
    int maxlen = len;
    maxlen = max(maxlen, __shfl_xor(maxlen, 16, 64));
    maxlen = max(maxlen, __shfl_xor(maxlen, 32, 64));

    // pass 1 (merged): online softmax max+denom+weighted g-sum
    float m = -3.4e38f, den = 0.f;
    float p[8];
#pragma unroll
    for (int q = 0; q < 8; q++) p[q] = 0.f;
    for (int i = 0; i < maxlen; ++i) {
      int r = min(r0 + i, r1 - 1);
      float ev = e[r];
      bf16x8 gv = *(const bf16x8*)(g + (size_t)r * DGAT + ld * 8);
      float evv = (i < len) ? ev : -3.4e38f;
      float mn = fmaxf(m, evv);
      float cor = __expf(m - mn);      // 0 on first iter; 1 when max unchanged
      float wr = __expf(evv - mn);     // 0 for padded rows
      den = den * cor + wr;
#pragma unroll
      for (int q = 0; q < 8; q++) p[q] = p[q] * cor + wr * (float)gv[q];
      m = mn;
    }
    float inv = 1.f / den;
#pragma unroll
    for (int q = 0; q < 8; q++) p[q] *= inv;
    // pass 2: residual + relu + segment max (mask to 0, no-op under max since om>=0)
    float om[8];
#pragma unroll
    for (int q = 0; q < 8; q++) om[q] = 0.f;
    for (int i = 0; i < maxlen; ++i) {
      int r = min(r0 + i, r1 - 1);
      bf16x8 hv = *(const bf16x8*)(h2 + (size_t)r * DGAT + ld * 8);
#pragma unroll
      for (int q = 0; q < 8; q++) {
        float a = fmaxf((float)hv[q] + p[q], 0.f);
        om[q] = fmaxf(om[q], (i < len) ? a : 0.f);
      }
    }
    bf16x8 ob;
#pragma unroll
    for (int q = 0; q < 8; q++) ob[q] = (bf16)om[q];
    int kofs = (ld * 8) ^ ((sl & 7) << 3);   // 8-aligned offset, XOR bits 3-5 -> stays 8-aligned
    *(bf16x8*)(objs + sl * 128 + kofs) = ob;
  }
  __syncthreads();

  // ---- proj phase: out[16 x 256] = obj @ pw + pb via MFMA
  f32x4 acc[4];
#pragma unroll
  for (int n = 0; n < 4; n++) acc[n] = zero;
#pragma unroll
  for (int ks = 0; ks < 4; ++ks) {
    const int kofs = ks * 32 + lh * 8;
    bf16x8 a = *(const bf16x8*)(objs + l15 * 128 + (kofs ^ ((l15 & 7) << 3)));
#pragma unroll
    for (int n = 0; n < 4; n++) {
      int c = w * 64 + n * 16 + l15;
      bf16x8 b = *(const bf16x8*)(pwt + (size_t)c * DGAT + kofs);
      acc[n] = __builtin_amdgcn_mfma_f32_16x16x32_bf16(b, a, acc[n], 0, 0, 0);
    }
  }
  float s2 = 0.f;
#pragma unroll
  for (int n = 0; n < 4; n++) {
    int c0 = w * 64 + n * 16 + lh * 4;
    f32x4 p4 = *(const f32x4*)(pb + c0);
#pragma unroll
    for (int q = 0; q < 4; q++) {
      acc[n][q] += p4[q];
      s2 += acc[n][q] * acc[n][q];
    }
  }
  s2 += __shfl_xor(s2, 16, 64);
  s2 += __shfl_xor(s2, 32, 64);
  if (l < 16) red[l * 4 + w] = s2;
  __syncthreads();
  float tot = red[l15 * 4 + 0] + red[l15 * 4 + 1] + red[l15 * 4 + 2] + red[l15 * 4 + 3];
  float rinv = 1.f / (sqrtf(tot) + 1e-9f);
#pragma unroll
  for (int n = 0; n < 4; n++) {
    int c0 = w * 64 + n * 16 + lh * 4;
    f32x4 o;
#pragma unroll
    for (int q = 0; q < 4; q++) o[q] = acc[n][q] * rinv;
    *(f32x4*)(out + (size_t)(gBase + l15) * DOUT + c0) = o;
  }
}

extern "C" void kernel_launch(void* const* d_in, const int* in_sizes, int n_in,
                              void* d_out, int out_size, void* d_ws, size_t ws_size,
                              hipStream_t stream) {
  const float* x    = (const float*)d_in[0];
  const int*   seg  = (const int*)d_in[1];
  const float* w2   = (const float*)d_in[2];
  const float* b2   = (const float*)d_in[3];
  const float* bn_g = (const float*)d_in[4];
  const float* bn_b = (const float*)d_in[5];
  const float* bn_m = (const float*)d_in[6];
  const float* bn_v = (const float*)d_in[7];
  const float* w3   = (const float*)d_in[8];
  const float* b3   = (const float*)d_in[9];
  const float* gw   = (const float*)d_in[10];
  const float* gb   = (const float*)d_in[11];
  const float* ga   = (const float*)d_in[12];
  const float* pw   = (const float*)d_in[13];
  const float* pb   = (const float*)d_in[14];

  char* ws = (char*)d_ws;
  bf16*  w2s = (bf16*)(ws + OFF_W2S);
  bf16*  w3t = (bf16*)(ws + OFF_W3T);
  bf16*  gwt = (bf16*)(ws + OFF_GWT);
  bf16*  pwt = (bf16*)(ws + OFF_PWT);
  float* bnS = (float*)(ws + OFF_BNS);
  float* bnB = (float*)(ws + OFF_BNB);
  int*   rs  = (int*)(ws + OFF_RS);
  bf16*  h2  = (bf16*)(ws + OFF_H2);
  bf16*  g   = (bf16*)(ws + OFF_G);
  float* e   = (float*)(ws + OFF_E);
  float* out = (float*)d_out;

  k_prep<<<NROWS / 256, 256, 0, stream>>>(w2, w3, gw, pw, b2, bn_g, bn_b, bn_m, bn_v,
                                          seg, w2s, w3t, gwt, pwt, bnS, bnB, rs);
  k_enc<<<NROWS / 128, 256, 0, stream>>>(x, w2s, w3t, gwt, bnS, bnB, b3, gb, ga, h2, g, e);
  k_segproj<<<GSEG / 16, 256, 0, stream>>>(e, g, h2, rs, pwt, pb, out);
}